// Round 14
// baseline (28.234 us; speedup 1.0000x reference)
//
#include <hip/hip_runtime.h>
#include <math.h>

#define NF 40
#define ED 64
#define NP 780      // 40*39/2
#define GPB 4       // batches per block (TWO waves each)
#define BT 512      // 8 waves
#define NTT 49      // 49 tiles x 16 pairs = 784 >= 780

typedef __attribute__((ext_vector_type(8))) _Float16 f16x8;
typedef __attribute__((ext_vector_type(2))) __fp16  fp16x2;
typedef __attribute__((ext_vector_type(4))) float   f32x4;

__global__ __launch_bounds__(BT, 2)   // R8 lesson: don't clamp VGPRs below need
void afm_mfma16k_kernel(const float* __restrict__ x,    // (B,40,64)
                        const float* __restrict__ W1,   // (64,64)
                        const float* __restrict__ b1,   // (64)
                        const float* __restrict__ W2,   // (1,64)
                        const float* __restrict__ Wl,   // (1,64)
                        const float* __restrict__ blp,  // (1)
                        float* __restrict__ out)        // (B,1)
{
    __shared__ __align__(16) unsigned char sxh[GPB * NF * 128];  // 20480 B
    __shared__ __align__(16) unsigned char sfrag[10 * 64 * 16];  // 10240 B
    __shared__ unsigned int srctw[1024];  // pre-swizzled {offr | offc<<16}, padded
    __shared__ float sred[8][2];          // per-wave {le, les}

    const int tid  = threadIdx.x;
    const int lane = tid & 63;
    const int w    = tid >> 6;        // wave id 0..7
    const int gb   = w >> 1;          // local batch 0..3
    const int half = w & 1;           // which half of the tile range
    const int ln15 = lane & 15;
    const int g    = lane >> 4;       // 0..3 : k-group / row-group
    const int cg   = g << 4;          // per-lane 16B slot offset (bits 4-5)

    const int b0 = blockIdx.x * GPB + gb;
    unsigned char* sxw = sxh + gb * (NF * 128);

    // ---- wave pair stages its batch's x -> fp16 LDS (5 float4 per lane) ----
    {
        const float4* xg = (const float4*)(x + (size_t)b0 * NF * ED);
        const int llp = half * 64 + lane;         // 0..127 within the pair
        #pragma unroll
        for (int i = 0; i < 5; ++i) {
            const int u = llp + i * 128;          // 640 float4 per batch
            float4 v = xg[u];
            const int r = u >> 4, j = u & 15;
            union { fp16x2 h2[2]; unsigned long long ll; } pk;
            pk.h2[0] = __builtin_amdgcn_cvt_pkrtz(v.x, v.y);
            pk.h2[1] = __builtin_amdgcn_cvt_pkrtz(v.z, v.w);
            const int byteoff = r * 128 + (((j >> 1) ^ (r & 7)) << 4) + (j & 1) * 8;
            *(unsigned long long*)(sxw + byteoff) = pk.ll;
        }
    }

    // ---- all 512 threads cooperatively build the 640 fragment slots ----
    for (int slot = tid; slot < 640; slot += BT) {
        const int f = slot >> 6, l = slot & 63;
        const int lg = l >> 4, l15 = l & 15;
        const float* src = (f < 8)
            ? (W1 + ((f >> 1) * 16 + l15) * ED + (f & 1) * 32 + lg * 8)
            : (Wl + (f - 8) * 32 + lg * 8);
        union { fp16x2 h2[4]; f16x8 h8; } u;
        u.h2[0] = __builtin_amdgcn_cvt_pkrtz(src[0], src[1]);
        u.h2[1] = __builtin_amdgcn_cvt_pkrtz(src[2], src[3]);
        u.h2[2] = __builtin_amdgcn_cvt_pkrtz(src[4], src[5]);
        u.h2[3] = __builtin_amdgcn_cvt_pkrtz(src[6], src[7]);
        *(f16x8*)(sfrag + slot * 16) = u.h8;
    }
    // ---- pre-swizzled (r,c) offset table, padded to 1024 entries ----
    for (int p = tid; p < 1024; p += BT) {
        const int pq = p < NP ? p : NP - 1;
        const int r = (int)((79.0f - sqrtf(6241.0f - 8.0f * (float)pq)) * 0.5f);
        const int c = pq - ((r * (79 - r)) >> 1) + r + 1;
        const unsigned int er = (unsigned int)((r << 7) | ((r & 7) << 4));
        const unsigned int ec = (unsigned int)((c << 7) | ((c & 7) << 4));
        srctw[p] = er | (ec << 16);
    }

    // ---- per-lane constants; w2 prescaled by log2(e) so exp2 replaces exp ----
    f32x4  b1v[4];
    fp16x2 w2h[4][2];
    #pragma unroll
    for (int mf = 0; mf < 4; ++mf) {
        float4 wv = *(const float4*)(W2 + mf * 16 + g * 4);
        b1v[mf] = *(const f32x4*)(b1 + mf * 16 + g * 4);
        const float L2E = 1.4426950408889634f;
        w2h[mf][0] = __builtin_amdgcn_cvt_pkrtz(wv.x * L2E, wv.y * L2E);
        w2h[mf][1] = __builtin_amdgcn_cvt_pkrtz(wv.z * L2E, wv.w * L2E);
    }
    const float blv = blp[0];

    __syncthreads();

    // ---- read shared fragments (identical per-lane across waves) ----
    f16x8 Ah[4][2], Awl[2];
    #pragma unroll
    for (int mf = 0; mf < 4; ++mf)
        #pragma unroll
        for (int ks = 0; ks < 2; ++ks)
            Ah[mf][ks] = *(const f16x8*)(sfrag + ((mf * 2 + ks) * 64 + lane) * 16);
    #pragma unroll
    for (int ks = 0; ks < 2; ++ks)
        Awl[ks] = *(const f16x8*)(sfrag + ((8 + ks) * 64 + lane) * 16);

    const f32x4 zero4 = {0.f, 0.f, 0.f, 0.f};
    const fp16x2 zh = {(__fp16)0.f, (__fp16)0.f};

    // ---- this wave's tiles [t0,t1), split into two independent chains ----
    const int t0 = half ? 25 : 0;
    const int t1 = half ? NTT : 25;
    const int tB = t0 + 13;           // chain B start (A: t0..t0+12, B: tB..t1-1)

    float leA = 0.f, lesA = 0.f, leB = 0.f, lesB = 0.f;
    for (int i = 0; i < 13; ++i) {
        const int tileA = t0 + i;
        const int tileB = tB + i;
        const int pA = tileA * 16 + ln15;
        const int pB = tileB * 16 + ln15;          // may overrun range; table padded

        // ---- both chains' loads issued together (2x LDS-level parallelism) ----
        const unsigned int rcA = srctw[pA];
        const unsigned int rcB = srctw[pB & 1023];
        const int offrA = (int)(rcA & 0xffffu) ^ cg;
        const int offcA = (int)(rcA >> 16) ^ cg;
        const int offrB = (int)(rcB & 0xffffu) ^ cg;
        const int offcB = (int)(rcB >> 16) ^ cg;
        f16x8 ar0 = *(const f16x8*)(sxw + offrA);
        f16x8 ar1 = *(const f16x8*)(sxw + (offrA ^ 64));
        f16x8 ac0 = *(const f16x8*)(sxw + offcA);
        f16x8 ac1 = *(const f16x8*)(sxw + (offcA ^ 64));
        f16x8 br0 = *(const f16x8*)(sxw + offrB);
        f16x8 br1 = *(const f16x8*)(sxw + (offrB ^ 64));
        f16x8 bc0 = *(const f16x8*)(sxw + offcB);
        f16x8 bc1 = *(const f16x8*)(sxw + (offcB ^ 64));

        f16x8 BfA0 = ar0 * ac0, BfA1 = ar1 * ac1;
        f16x8 BfB0 = br0 * bc0, BfB1 = br1 * bc1;

        // ---- s_p for both chains (Wl broadcast A) ----
        f32x4 saccA, saccB;
        saccA = __builtin_amdgcn_mfma_f32_16x16x32_f16(Awl[0], BfA0, zero4, 0, 0, 0);
        saccB = __builtin_amdgcn_mfma_f32_16x16x32_f16(Awl[0], BfB0, zero4, 0, 0, 0);
        saccA = __builtin_amdgcn_mfma_f32_16x16x32_f16(Awl[1], BfA1, saccA, 0, 0, 0);
        saccB = __builtin_amdgcn_mfma_f32_16x16x32_f16(Awl[1], BfB1, saccB, 0, 0, 0);

        // ---- h for both chains ----
        f32x4 accA[4], accB[4];
        #pragma unroll
        for (int mf = 0; mf < 4; ++mf) {
            accA[mf] = __builtin_amdgcn_mfma_f32_16x16x32_f16(Ah[mf][0], BfA0, b1v[mf], 0, 0, 0);
            accB[mf] = __builtin_amdgcn_mfma_f32_16x16x32_f16(Ah[mf][0], BfB0, b1v[mf], 0, 0, 0);
        }
        #pragma unroll
        for (int mf = 0; mf < 4; ++mf) {
            accA[mf] = __builtin_amdgcn_mfma_f32_16x16x32_f16(Ah[mf][1], BfA1, accA[mf], 0, 0, 0);
            accB[mf] = __builtin_amdgcn_mfma_f32_16x16x32_f16(Ah[mf][1], BfB1, accB[mf], 0, 0, 0);
        }

        // ---- epilogues, interleaved by the scheduler (independent chains) ----
        float qA0 = 0.f, qA1 = 0.f, qB0 = 0.f, qB1 = 0.f;
        #pragma unroll
        for (int mf = 0; mf < 4; ++mf) {
            fp16x2 a01 = __builtin_amdgcn_cvt_pkrtz(accA[mf][0], accA[mf][1]);
            fp16x2 a23 = __builtin_amdgcn_cvt_pkrtz(accA[mf][2], accA[mf][3]);
            fp16x2 b01 = __builtin_amdgcn_cvt_pkrtz(accB[mf][0], accB[mf][1]);
            fp16x2 b23 = __builtin_amdgcn_cvt_pkrtz(accB[mf][2], accB[mf][3]);
            a01 = __builtin_elementwise_max(a01, zh);
            a23 = __builtin_elementwise_max(a23, zh);
            b01 = __builtin_elementwise_max(b01, zh);
            b23 = __builtin_elementwise_max(b23, zh);
            if (mf & 1) {
                qA1 = __builtin_amdgcn_fdot2(a01, w2h[mf][0], qA1, false);
                qA1 = __builtin_amdgcn_fdot2(a23, w2h[mf][1], qA1, false);
                qB1 = __builtin_amdgcn_fdot2(b01, w2h[mf][0], qB1, false);
                qB1 = __builtin_amdgcn_fdot2(b23, w2h[mf][1], qB1, false);
            } else {
                qA0 = __builtin_amdgcn_fdot2(a01, w2h[mf][0], qA0, false);
                qA0 = __builtin_amdgcn_fdot2(a23, w2h[mf][1], qA0, false);
                qB0 = __builtin_amdgcn_fdot2(b01, w2h[mf][0], qB0, false);
                qB0 = __builtin_amdgcn_fdot2(b23, w2h[mf][1], qB0, false);
            }
        }
        float pa = qA0 + qA1, pb = qB0 + qB1;
        pa += __shfl_xor(pa, 16);
        pb += __shfl_xor(pb, 16);
        pa += __shfl_xor(pa, 32);
        pb += __shfl_xor(pb, 32);

        const float eA = (pA < NP) ? exp2f(pa) : 0.f;
        const float eB = (tileB < t1 && pB < NP) ? exp2f(pb) : 0.f;
        leA += eA;  lesA = fmaf(eA, saccA[0], lesA);
        leB += eB;  lesB = fmaf(eB, saccB[0], lesB);
    }

    float le = leA + leB, les = lesA + lesB;
    // reduce over ln15 within 16-lane groups (g-copies identical; each pair once)
    #pragma unroll
    for (int off = 1; off < 16; off <<= 1) {
        le  += __shfl_xor(le, off);
        les += __shfl_xor(les, off);
    }
    if (lane == 0) { sred[w][0] = le; sred[w][1] = les; }
    __syncthreads();

    // combine the wave pair and write the scalar
    if (half == 0 && lane == 0) {
        const float E  = sred[w][0] + sred[w + 1][0];
        const float ES = sred[w][1] + sred[w + 1][1];
        out[b0] = ES / E + blv;
    }
}

extern "C" void kernel_launch(void* const* d_in, const int* in_sizes, int n_in,
                              void* d_out, int out_size, void* d_ws, size_t ws_size,
                              hipStream_t stream) {
    const float* x  = (const float*)d_in[0];
    const float* W1 = (const float*)d_in[1];
    const float* b1 = (const float*)d_in[2];
    const float* W2 = (const float*)d_in[3];
    // d_in[4] = b2 : cancels in softmax, unused
    const float* Wl = (const float*)d_in[5];
    const float* bl = (const float*)d_in[6];
    float* out = (float*)d_out;

    const int B = in_sizes[0] / (NF * ED);   // 2048
    afm_mfma16k_kernel<<<B / GPB, BT, 0, stream>>>(x, W1, b1, W2, Wl, bl, out);
}

// Round 15
// 27.355 us; speedup vs baseline: 1.0321x; 1.0321x over previous
//
#include <hip/hip_runtime.h>
#include <math.h>

#define NF 40
#define ED 64
#define NP 780      // 40*39/2
#define GPB 2       // batches per block (FOUR waves each) -> grid 1024 = 4 blocks/CU
#define BT 512      // 8 waves
#define NTT 49      // 49 tiles x 16 pairs = 784 >= 780

typedef __attribute__((ext_vector_type(8))) _Float16 f16x8;
typedef __attribute__((ext_vector_type(2))) __fp16  fp16x2;
typedef __attribute__((ext_vector_type(4))) float   f32x4;

__global__ __launch_bounds__(BT, 2)   // R8 lesson: don't clamp VGPRs below need
void afm_mfma16l_kernel(const float* __restrict__ x,    // (B,40,64)
                        const float* __restrict__ W1,   // (64,64)
                        const float* __restrict__ b1,   // (64)
                        const float* __restrict__ W2,   // (1,64)
                        const float* __restrict__ Wl,   // (1,64)
                        const float* __restrict__ blp,  // (1)
                        float* __restrict__ out)        // (B,1)
{
    __shared__ __align__(16) unsigned char sxh[GPB * NF * 128];  // 10240 B
    __shared__ __align__(16) unsigned char sfrag[10 * 64 * 16];  // 10240 B
    __shared__ unsigned int srctw[784];   // pre-swizzled {offr | offc<<16}
    __shared__ float sred[8][2];          // per-wave {le, les}
    // total ~23.8 KB -> 6 blocks/CU by LDS; grid 1024 -> 4 blocks/CU resident

    const int tid  = threadIdx.x;
    const int lane = tid & 63;
    const int w    = tid >> 6;        // wave id 0..7
    const int gb   = w >> 2;          // local batch 0..1
    const int q    = w & 3;           // quarter of the tile range
    const int ln15 = lane & 15;
    const int g    = lane >> 4;       // 0..3 : k-group / row-group
    const int cg   = g << 4;          // per-lane 16B slot offset (bits 4-5)

    const int b0 = blockIdx.x * GPB + gb;
    unsigned char* sxw = sxh + gb * (NF * 128);

    // ---- the 4 waves of a batch co-stage its x -> fp16 LDS (<=3 f4/lane) ----
    {
        const float4* xg = (const float4*)(x + (size_t)b0 * NF * ED);
        const int base = q * 64 + lane;           // 0..255 within the quad
        #pragma unroll
        for (int i = 0; i < 3; ++i) {
            const int u = base + i * 256;         // 640 float4 per batch
            if (u < NF * 16) {
                float4 v = xg[u];
                const int r = u >> 4, j = u & 15;
                union { fp16x2 h2[2]; unsigned long long ll; } pk;
                pk.h2[0] = __builtin_amdgcn_cvt_pkrtz(v.x, v.y);
                pk.h2[1] = __builtin_amdgcn_cvt_pkrtz(v.z, v.w);
                const int byteoff = r * 128 + (((j >> 1) ^ (r & 7)) << 4) + (j & 1) * 8;
                *(unsigned long long*)(sxw + byteoff) = pk.ll;
            }
        }
    }

    // ---- all 512 threads cooperatively build the 640 fragment slots ----
    for (int slot = tid; slot < 640; slot += BT) {
        const int f = slot >> 6, l = slot & 63;
        const int lg = l >> 4, l15 = l & 15;
        const float* src = (f < 8)
            ? (W1 + ((f >> 1) * 16 + l15) * ED + (f & 1) * 32 + lg * 8)
            : (Wl + (f - 8) * 32 + lg * 8);
        union { fp16x2 h2[4]; f16x8 h8; } u;
        u.h2[0] = __builtin_amdgcn_cvt_pkrtz(src[0], src[1]);
        u.h2[1] = __builtin_amdgcn_cvt_pkrtz(src[2], src[3]);
        u.h2[2] = __builtin_amdgcn_cvt_pkrtz(src[4], src[5]);
        u.h2[3] = __builtin_amdgcn_cvt_pkrtz(src[6], src[7]);
        *(f16x8*)(sfrag + slot * 16) = u.h8;
    }
    // ---- pre-swizzled (r,c) offset table (784 entries, pads past NP) ----
    for (int p = tid; p < 784; p += BT) {
        const int pq = p < NP ? p : NP - 1;
        const int r = (int)((79.0f - sqrtf(6241.0f - 8.0f * (float)pq)) * 0.5f);
        const int c = pq - ((r * (79 - r)) >> 1) + r + 1;
        const unsigned int er = (unsigned int)((r << 7) | ((r & 7) << 4));
        const unsigned int ec = (unsigned int)((c << 7) | ((c & 7) << 4));
        srctw[p] = er | (ec << 16);
    }

    // ---- per-lane constants; w2 prescaled by log2(e) so exp2 replaces exp ----
    f32x4  b1v[4];
    fp16x2 w2h[4][2];
    #pragma unroll
    for (int mf = 0; mf < 4; ++mf) {
        float4 wv = *(const float4*)(W2 + mf * 16 + g * 4);
        b1v[mf] = *(const f32x4*)(b1 + mf * 16 + g * 4);
        const float L2E = 1.4426950408889634f;
        w2h[mf][0] = __builtin_amdgcn_cvt_pkrtz(wv.x * L2E, wv.y * L2E);
        w2h[mf][1] = __builtin_amdgcn_cvt_pkrtz(wv.z * L2E, wv.w * L2E);
    }
    const float blv = blp[0];

    __syncthreads();

    // ---- read shared fragments (identical per-lane across waves) ----
    f16x8 Ah[4][2], Awl[2];
    #pragma unroll
    for (int mf = 0; mf < 4; ++mf)
        #pragma unroll
        for (int ks = 0; ks < 2; ++ks)
            Ah[mf][ks] = *(const f16x8*)(sfrag + ((mf * 2 + ks) * 64 + lane) * 16);
    #pragma unroll
    for (int ks = 0; ks < 2; ++ks)
        Awl[ks] = *(const f16x8*)(sfrag + ((8 + ks) * 64 + lane) * 16);

    const f32x4 zero4 = {0.f, 0.f, 0.f, 0.f};
    const fp16x2 zh = {(__fp16)0.f, (__fp16)0.f};

    // ---- this wave's quarter of the 49 tiles: 13,12,12,12 ----
    const int t0 = q == 0 ? 0 : 13 + 12 * (q - 1);
    const int t1 = t0 + (q == 0 ? 13 : 12);

    float le = 0.f, les = 0.f;
    for (int tile = t0; tile < t1; ++tile) {
        const int p = tile * 16 + ln15;            // < 784
        const unsigned int rc = srctw[p];
        const int offr = (int)(rc & 0xffffu) ^ cg;
        const int offc = (int)(rc >> 16) ^ cg;
        f16x8 xr0 = *(const f16x8*)(sxw + offr);
        f16x8 xr1 = *(const f16x8*)(sxw + (offr ^ 64));
        f16x8 xc0 = *(const f16x8*)(sxw + offc);
        f16x8 xc1 = *(const f16x8*)(sxw + (offc ^ 64));
        f16x8 Bf0 = xr0 * xc0;                     // 4x v_pk_mul_f16 each
        f16x8 Bf1 = xr1 * xc1;

        // s_p = inner_p . Wl on the MFMA pipe (Wl broadcast A)
        f32x4 sacc;
        sacc = __builtin_amdgcn_mfma_f32_16x16x32_f16(Awl[0], Bf0, zero4, 0, 0, 0);
        sacc = __builtin_amdgcn_mfma_f32_16x16x32_f16(Awl[1], Bf1, sacc, 0, 0, 0);

        // h^T = W1 @ inner^T + b1 (b1 seeded through the MFMA C operand)
        f32x4 acc[4];
        #pragma unroll
        for (int mf = 0; mf < 4; ++mf) {
            acc[mf] = __builtin_amdgcn_mfma_f32_16x16x32_f16(Ah[mf][0], Bf0, b1v[mf], 0, 0, 0);
            acc[mf] = __builtin_amdgcn_mfma_f32_16x16x32_f16(Ah[mf][1], Bf1, acc[mf], 0, 0, 0);
        }

        // logit*log2e = sum_m w2[m]*relu(h[m][p]) via pkrtz + pk_max + fdot2
        float q0 = 0.f, q1 = 0.f;
        #pragma unroll
        for (int mf = 0; mf < 4; ++mf) {
            fp16x2 h01 = __builtin_amdgcn_cvt_pkrtz(acc[mf][0], acc[mf][1]);
            fp16x2 h23 = __builtin_amdgcn_cvt_pkrtz(acc[mf][2], acc[mf][3]);
            h01 = __builtin_elementwise_max(h01, zh);
            h23 = __builtin_elementwise_max(h23, zh);
            if (mf & 1) {
                q1 = __builtin_amdgcn_fdot2(h01, w2h[mf][0], q1, false);
                q1 = __builtin_amdgcn_fdot2(h23, w2h[mf][1], q1, false);
            } else {
                q0 = __builtin_amdgcn_fdot2(h01, w2h[mf][0], q0, false);
                q0 = __builtin_amdgcn_fdot2(h23, w2h[mf][1], q0, false);
            }
        }
        float part = q0 + q1;
        part += __shfl_xor(part, 16);      // cross-g on the LDS pipe (R12 lesson)
        part += __shfl_xor(part, 32);

        // fused softmax accumulation (no max-sub: logits O(1), validated R7)
        const float e_ = (p < NP) ? exp2f(part) : 0.f;
        le  += e_;
        les  = fmaf(e_, sacc[0], les);
    }

    // reduce over ln15 within 16-lane groups (g-copies identical; each pair once)
    #pragma unroll
    for (int off = 1; off < 16; off <<= 1) {
        le  += __shfl_xor(le, off);
        les += __shfl_xor(les, off);
    }
    if (lane == 0) { sred[w][0] = le; sred[w][1] = les; }
    __syncthreads();

    // combine the batch's 4 waves and write the scalar
    if (q == 0 && lane == 0) {
        const float E  = sred[w][0] + sred[w + 1][0] + sred[w + 2][0] + sred[w + 3][0];
        const float ES = sred[w][1] + sred[w + 1][1] + sred[w + 2][1] + sred[w + 3][1];
        out[b0] = ES / E + blv;
    }
}

extern "C" void kernel_launch(void* const* d_in, const int* in_sizes, int n_in,
                              void* d_out, int out_size, void* d_ws, size_t ws_size,
                              hipStream_t stream) {
    const float* x  = (const float*)d_in[0];
    const float* W1 = (const float*)d_in[1];
    const float* b1 = (const float*)d_in[2];
    const float* W2 = (const float*)d_in[3];
    // d_in[4] = b2 : cancels in softmax, unused
    const float* Wl = (const float*)d_in[5];
    const float* bl = (const float*)d_in[6];
    float* out = (float*)d_out;

    const int B = in_sizes[0] / (NF * ED);   // 2048
    afm_mfma16l_kernel<<<B / GPB, BT, 0, stream>>>(x, W1, b1, W2, Wl, bl, out);
}